// Round 11
// baseline (377.859 us; speedup 1.0000x reference)
//
#include <hip/hip_runtime.h>
#include <math.h>

#define NODES 768
#define BB 4
#define TT 12
#define FF 32
#define HH 64
#define EE 24576
#define EPSV 1e-5f

typedef short bf16x8 __attribute__((ext_vector_type(8)));
typedef float f32x4  __attribute__((ext_vector_type(4)));

__device__ __forceinline__ unsigned short f2bf(float f) {
  union { float f; unsigned int u; } c; c.f = f;
  unsigned int u = c.u;
  unsigned int r = (u + 0x7FFFu + ((u >> 16) & 1u)) >> 16;   // RTNE
  return (unsigned short)r;
}

// ---- workspace layout (float index units) ----
constexpr int OFF_ROWPTR = 1600;     // int[769]
constexpr int OFF_COLS   = 3200;     // int[24576]
constexpr int OFF_WSEW   = 27776;    // float[24576]
constexpr int OFF_WT     = 52352;    // ushort[4*36864] tconv B-fragments [lj][ks][nt][lane][j] (bf16)
constexpr int OFF_THT    = 199808;   // float[2*2*64*64] thetaT [l][k][o][i]
constexpr int OFF_WIN    = 216192;   // float[64*32]    in_proj^T [o][i]
constexpr int OFF_GW     = 222336;   // float[34]: gw[32], S1, S2
constexpr int OFF_H      = 222400;   // float[2359296]
constexpr int OFF_ZA     = 2581696;  // float[2359296]
constexpr int OFF_ZB     = 4940992;  // float[2359296]
constexpr int OFF_AGG    = 7300288;  // float[2359296]
constexpr int OFF_A      = 9661120;  // float[3072*32]
constexpr int OFF_C      = 9759424;  // float[3072*32]

// ---------------- prep: weight packing + gw precompute ----------------
__global__ void prep_kernel(const float* __restrict__ tc_w, const float* __restrict__ cheb_w,
                            const float* __restrict__ in_proj_w, const float* __restrict__ out1_w,
                            const float* __restrict__ oln_g, const float* __restrict__ oln_b,
                            const float* __restrict__ out2_w, float* __restrict__ ws) {
  int idx = blockIdx.x * 256 + threadIdx.x;
  if (idx < 147456) {
    // bf16 B-fragment pack: [lj][ks(6)][nt(12)][lane(64)][j(8)]
    int lj = idx / 36864; int r = idx % 36864;
    int ks = r / 6144;    int r2 = r % 6144;
    int nt = r2 / 512;    int r3 = r2 % 512;
    int l  = r3 >> 3;     int j  = r3 & 7;
    int k  = ks * 32 + ((l >> 4) << 3) + j;   // K index 0..191
    int kk = k >> 6;      int in = k & 63;
    int col = nt * 16 + (l & 15);             // N index 0..191
    int g = col >> 6;     int o  = col & 63;
    float v = tc_w[(((lj * 3 + g) * 64 + o) * 64 + in) * 3 + kk];
    ((unsigned short*)(ws + OFF_WT))[idx] = f2bf(v);
  }
  int idx2 = idx - 147456;
  if (idx2 >= 0 && idx2 < 16384) {
    int i = idx2 & 63; int t = idx2 >> 6;
    int o = t & 63; t >>= 6;
    int k = t & 1; int l = t >> 1;
    ws[OFF_THT + idx2] = cheb_w[((l*2 + k)*64 + i)*64 + o];
  }
  int idx3 = idx2 - 16384;
  if (idx3 >= 0 && idx3 < 2048) {
    int i = idx3 & 31; int o = idx3 >> 5;
    ws[OFF_WIN + idx3] = in_proj_w[i*64 + o];
  }
  int idx6 = idx3 - 2048;
  if (idx6 == 0) {
    float S1 = 0.f, S2 = 0.f;
    for (int d = 0; d < 32; d++) {
      float gw = oln_g[d] * out2_w[d];
      ws[OFF_GW + d] = gw;
      S1 += gw;
      S2 += oln_b[d] * out2_w[d];
    }
    ws[OFF_GW + 32] = S1;
    ws[OFF_GW + 33] = S2;
  }
}

// ---------------- fused CSR build: count + scan + scatter (1 block) ----------------
__global__ __launch_bounds__(1024) void graph_kernel(const int* __restrict__ ei,
                                                     const float* __restrict__ ew,
                                                     float* __restrict__ ws) {
  __shared__ float sdeg[NODES];
  __shared__ int scnt[NODES];
  __shared__ int soff[NODES];
  __shared__ int sscan[NODES];
  int tid = threadIdx.x;
  if (tid < NODES) { sdeg[tid] = 0.f; scnt[tid] = 0; }
  __syncthreads();
  for (int e = tid; e < EE; e += 1024) {
    int r = ei[e];
    atomicAdd(&sdeg[r], ew[e]);
    atomicAdd(&scnt[r], 1);
  }
  __syncthreads();
  int c = (tid < NODES) ? scnt[tid] : 0;
  if (tid < NODES) sscan[tid] = c;
  __syncthreads();
  for (int d = 1; d < NODES; d <<= 1) {
    int v = 0;
    if (tid < NODES && tid >= d) v = sscan[tid - d];
    __syncthreads();
    if (tid < NODES) sscan[tid] += v;
    __syncthreads();
  }
  if (tid < NODES) {
    soff[tid] = sscan[tid] - c;
    ((int*)ws)[OFF_ROWPTR + tid + 1] = sscan[tid];
    if (tid == 0) ((int*)ws)[OFF_ROWPTR] = 0;
  }
  __syncthreads();
  for (int e = tid; e < EE; e += 1024) {
    int r = ei[e];
    int col = ei[EE + e];
    float w = ew[e];
    float dr = sdeg[r], dc = sdeg[col];
    float dir = dr > 0.f ? rsqrtf(fmaxf(dr, 1e-12f)) : 0.f;
    float dic = dc > 0.f ? rsqrtf(fmaxf(dc, 1e-12f)) : 0.f;
    float lw = -dir * w * dic;
    int pos = atomicAdd(&soff[r], 1);
    ((int*)ws)[OFF_COLS + pos] = col;
    ws[OFF_WSEW + pos] = lw;
  }
}

// ---------------- in_proj: h = x @ W(32x64) + b  [o-split x4, reg-resident rows] ----------------
__global__ __launch_bounds__(64) void inproj_kernel(const float* __restrict__ x,
                                                    const float* __restrict__ in_proj_b,
                                                    float* __restrict__ ws) {
  int bid = blockIdx.x;
  int r0 = (bid >> 2) << 6;
  int o0 = (bid & 3) << 4;
  int row = r0 + threadIdx.x;
  float xr[32];
  const float4* xp = (const float4*)(x + row * 32);
#pragma unroll
  for (int i = 0; i < 8; i++) {
    float4 v = xp[i];
    xr[4*i] = v.x; xr[4*i+1] = v.y; xr[4*i+2] = v.z; xr[4*i+3] = v.w;
  }
  const float* WT = ws + OFF_WIN;
  float* h = ws + OFF_H;
  float4 res[4];
  float* rf = (float*)res;
#pragma unroll
  for (int oo = 0; oo < 16; oo++) {
    int o = o0 + oo;
    float acc = in_proj_b[o];
#pragma unroll
    for (int i = 0; i < 32; i++) acc += xr[i] * WT[o * 32 + i];
    rf[oo] = acc;
  }
  float4* op = (float4*)(h + row * 64 + o0);
#pragma unroll
  for (int q = 0; q < 4; q++) op[q] = res[q];
}

// ---------------- gated temporal conv via bf16 MFMA [3 pairs/block, grid 1024] ----------------
__global__ __launch_bounds__(256) void tconv_kernel(const float* __restrict__ src,
                                                    float* __restrict__ dst,
                                                    const unsigned short* __restrict__ WB,
                                                    const float* __restrict__ bias) {
  __shared__ unsigned short zls[3072];   // 6144 B: 3 pairs x 14 rows x 128 B (+tail slack)
  __shared__ float cbuf[12 * 192];       // 9216 B
  unsigned char* zb = (unsigned char*)zls;
  int tid = threadIdx.x;
  int lane = tid & 63;
  int w = tid >> 6;
  int P0 = blockIdx.x * 3;
  int b  = P0 / NODES;
  int n0 = P0 % NODES;

  // ---- preload B fragments: 6 ksteps x 3 owned ntiles ----
  bf16x8 bfr[6][3];
#pragma unroll
  for (int ks = 0; ks < 6; ks++) {
#pragma unroll
    for (int c = 0; c < 3; c++) {
      int nt = w * 3 + c;
      bfr[ks][c] = *(const bf16x8*)(WB + (((ks * 12 + nt) * 64 + lane) << 3));
    }
  }
  float B0 = bias[tid & 63];
  float B1 = bias[64 + (tid & 63)];
  float B2 = bias[128 + (tid & 63)];

  // ---- zero halo rows ts=0,13 per pair ----
  for (int e = tid; e < 384; e += 256) {
    int pl = e / 128; int rr = (e >> 6) & 1; int in = e & 63;
    int ts = rr ? 13 : 0;
    int off = pl * 1792 + ts * 128 + ((in * 2) ^ ((ts & 7) << 4));
    *(unsigned short*)(zb + off) = 0;
  }
  // ---- stage z vectorized: float4 load -> 2x u32 packed bf16 stores ----
  for (int e = tid; e < 576; e += 256) {
    int pl = e / 192; int rem = e % 192; int t = rem >> 4; int i4 = rem & 15;
    int c0 = i4 << 2;
    float4 v = *(const float4*)(src + ((b * TT + t) * NODES + n0 + pl) * HH + c0);
    int ts = t + 1;
    int base = pl * 1792 + ts * 128;
    unsigned int lo = ((unsigned int)f2bf(v.y) << 16) | f2bf(v.x);
    unsigned int hi = ((unsigned int)f2bf(v.w) << 16) | f2bf(v.z);
    *(unsigned int*)(zb + (base + (((c0    ) * 2) ^ ((ts & 7) << 4)))) = lo;
    *(unsigned int*)(zb + (base + (((c0 + 2) * 2) ^ ((ts & 7) << 4)))) = hi;
  }
  __syncthreads();

  int tb = (lane >> 4) << 2;
  int cc = lane & 15;
  for (int p = 0; p < 3; p++) {
    bf16x8 afr[6];
#pragma unroll
    for (int ks = 0; ks < 6; ks++) {
      int k0 = ks * 32 + ((lane >> 4) << 3);
      int kk = k0 >> 6; int in0 = k0 & 63;
      int ts = (lane & 15) + kk;
      int off = p * 1792 + ts * 128 + ((in0 * 2) ^ ((ts & 7) << 4));
      afr[ks] = *(const bf16x8*)(zb + off);
    }
    f32x4 a0 = {0.f, 0.f, 0.f, 0.f};
    f32x4 a1 = a0, a2 = a0;
#pragma unroll
    for (int ks = 0; ks < 6; ks++) {
      a0 = __builtin_amdgcn_mfma_f32_16x16x32_bf16(afr[ks], bfr[ks][0], a0, 0, 0, 0);
      a1 = __builtin_amdgcn_mfma_f32_16x16x32_bf16(afr[ks], bfr[ks][1], a1, 0, 0, 0);
      a2 = __builtin_amdgcn_mfma_f32_16x16x32_bf16(afr[ks], bfr[ks][2], a2, 0, 0, 0);
    }
    __syncthreads();   // previous pair's gating finished reading cbuf
#pragma unroll
    for (int r = 0; r < 4; r++) {
      int t = tb + r;
      if (t < 12) {
        cbuf[t * 192 + (w * 3 + 0) * 16 + cc] = a0[r];
        cbuf[t * 192 + (w * 3 + 1) * 16 + cc] = a1[r];
        cbuf[t * 192 + (w * 3 + 2) * 16 + cc] = a2[r];
      }
    }
    __syncthreads();
    int o = tid & 63;
    int n = n0 + p;
#pragma unroll
    for (int m = 0; m < 3; m++) {
      int t = (tid >> 6) + (m << 2);
      float v0 = cbuf[t * 192 + o]       + B0;
      float v1 = cbuf[t * 192 + 64 + o]  + B1;
      float v2 = cbuf[t * 192 + 128 + o] + B2;
      float g = 1.f / (1.f + __expf(-v1));
      dst[((b * TT + t) * NODES + n) * HH + o] = fmaxf(v0 * g + v2, 0.f);
    }
  }
}

// ---------------- graph aggregation [bt-split x2] ----------------
__global__ __launch_bounds__(256) void agg_kernel(const float* __restrict__ za,
                                                  float* __restrict__ agg,
                                                  const float* __restrict__ ws) {
  int n = blockIdx.x >> 1;
  int half = blockIdx.x & 1;
  const int* rowptr = (const int*)ws + OFF_ROWPTR;
  const int* cols = (const int*)ws + OFF_COLS;
  const float* wsrt = ws + OFF_WSEW;
  int e0 = rowptr[n], e1 = rowptr[n + 1];
  int tid = threadIdx.x;
  int hh = tid & 63;
  int bt0 = tid >> 6;
  float acc[6];
#pragma unroll
  for (int p = 0; p < 6; p++) acc[p] = 0.f;
  for (int e = e0; e < e1; e++) {
    int c = cols[e];
    float w = wsrt[e];
    const float* zp = za + c * HH + hh;
#pragma unroll
    for (int p = 0; p < 6; p++) {
      int bt = bt0 + (((half * 6) + p) << 2);
      acc[p] += w * zp[bt * NODES * HH];
    }
  }
#pragma unroll
  for (int p = 0; p < 6; p++) {
    int bt = bt0 + (((half * 6) + p) << 2);
    agg[(bt * NODES + n) * HH + hh] = acc[p];
  }
}

// ---------------- cheb combine [o-split x4, reg-resident rows] ----------------
__global__ __launch_bounds__(64) void cheb_kernel(const float* __restrict__ za,
                                                  const float* __restrict__ agg,
                                                  float* __restrict__ zb,
                                                  const float* __restrict__ thetaT,
                                                  const float* __restrict__ bias) {
  int bid = blockIdx.x;
  int r0 = (bid >> 2) << 6;
  int o0 = (bid & 3) << 4;
  int row = r0 + threadIdx.x;
  float xz[64], xa[64];
  const float4* zp = (const float4*)(za + row * 64);
  const float4* ap = (const float4*)(agg + row * 64);
#pragma unroll
  for (int i = 0; i < 16; i++) {
    float4 v = zp[i];
    xz[4*i] = v.x; xz[4*i+1] = v.y; xz[4*i+2] = v.z; xz[4*i+3] = v.w;
    float4 w = ap[i];
    xa[4*i] = w.x; xa[4*i+1] = w.y; xa[4*i+2] = w.z; xa[4*i+3] = w.w;
  }
  float4 res[4];
  float* rf = (float*)res;
#pragma unroll
  for (int oo = 0; oo < 16; oo++) {
    int o = o0 + oo;
    float acc = bias[o];
    const float* t0 = thetaT + o * 64;
    const float* t1 = thetaT + 4096 + o * 64;
#pragma unroll
    for (int i = 0; i < 64; i++) acc += xz[i] * t0[i] + xa[i] * t1[i];
    rf[oo] = fmaxf(acc, 0.f);
  }
  float4* op = (float4*)(zb + row * 64 + o0);
#pragma unroll
  for (int q = 0; q < 4; q++) op[q] = res[q];
}

// ---------------- fused BN stats + BN apply + LN + residual (per node) ----------------
__global__ __launch_bounds__(256) void bn_kernel(const float* __restrict__ z,
                                                 float* __restrict__ h,
                                                 const float* __restrict__ bn_g,
                                                 const float* __restrict__ bn_b,
                                                 const float* __restrict__ ln_g,
                                                 const float* __restrict__ ln_b) {
  __shared__ float zl[48 * 64];   // 12 KB node tile
  __shared__ float rs[4], rss[4];
  __shared__ float sstat[2];
  int n = blockIdx.x;
  int tid = threadIdx.x;
  int wave = tid >> 6, lane = tid & 63;
  float s = 0.f, ss = 0.f;
  for (int p = tid; p < 3072; p += 256) {
    int bt = p >> 6, hh = p & 63;
    float v = z[(bt * NODES + n) * HH + hh];
    zl[p] = v;
    s += v; ss += v * v;
  }
#pragma unroll
  for (int d = 32; d >= 1; d >>= 1) { s += __shfl_down(s, d, 64); ss += __shfl_down(ss, d, 64); }
  if (lane == 0) { rs[wave] = s; rss[wave] = ss; }
  __syncthreads();
  if (tid == 0) {
    float S = rs[0] + rs[1] + rs[2] + rs[3];
    float SS = rss[0] + rss[1] + rss[2] + rss[3];
    float m = S / 3072.f;
    float var = SS / 3072.f - m * m;
    sstat[0] = m; sstat[1] = rsqrtf(var + EPSV);
  }
  __syncthreads();
  float mu = sstat[0], rstd = sstat[1];
  float bg = bn_g[n] * rstd;
  float bbb = bn_b[n] - mu * bg;
  float lg = ln_g[lane], lb = ln_b[lane];
  for (int k = 0; k < 12; k++) {
    int bt = wave + (k << 2);
    float v = zl[bt * 64 + lane] * bg + bbb;
    float s1 = v, s2 = v * v;
#pragma unroll
    for (int d = 32; d >= 1; d >>= 1) { s1 += __shfl_xor(s1, d, 64); s2 += __shfl_xor(s2, d, 64); }
    float m = s1 * (1.f / 64.f);
    float var = s2 * (1.f / 64.f) - m * m;
    float r2 = rsqrtf(var + EPSV);
    v = (v - m) * r2 * lg + lb;
    h[(bt * NODES + n) * HH + lane] += v;
  }
}

// ---------------- out projection: one output per thread ----------------
__global__ __launch_bounds__(256) void proj_kernel(const float* __restrict__ out1_w,
                                                   const float* __restrict__ out1_b,
                                                   float* __restrict__ ws) {
  __shared__ float wl[128 * 32];   // raw [i][o] layout, 16 KB
  __shared__ float rl[4][64];
  int r0 = blockIdx.x * 4;
  int tid = threadIdx.x;
  const float* h = ws + OFF_H;
  for (int p = tid; p < 4096; p += 256) wl[p] = out1_w[p];
  {
    int rr = tid >> 6, ii = tid & 63;
    int row = r0 + rr;
    int b = row / NODES, n = row % NODES;
    rl[rr][ii] = h[((b * TT + (TT - 1)) * NODES + n) * 64 + ii];
  }
  __syncthreads();
  int rr = tid >> 6;        // wave = row
  int o = tid & 63;         // lane = output
  int part = o >> 5, oc = o & 31;
  float acc = part ? out1_b[oc] : 0.f;
  const float* wcol = wl + part * 64 * 32;
#pragma unroll
  for (int i = 0; i < 64; i++) acc += rl[rr][i] * wcol[i * 32 + oc];
  int row = r0 + rr;
  if (part == 0) (ws + OFF_A)[row * 32 + oc] = acc;
  else           (ws + OFF_C)[row * 32 + oc] = acc;
}

// ---------------- final pairwise head ----------------
__global__ __launch_bounds__(256) void pair_kernel(const float* __restrict__ ws,
                                                   const float* __restrict__ out2_b,
                                                   float* __restrict__ out) {
  __shared__ float al[16 * 33], cl[16 * 33], gwl[34];
  int bidx = blockIdx.x;
  int b = bidx / (48 * 48);
  int rem = bidx % (48 * 48);
  int i0 = (rem / 48) * 16;
  int j0 = (rem % 48) * 16;
  int tid = threadIdx.x;
  const float* abuf = ws + OFF_A;
  const float* cbuf = ws + OFF_C;
  if (tid < 34) gwl[tid] = ws[OFF_GW + tid];
  for (int p = tid; p < 512; p += 256) {
    int rr = p >> 5, dd = p & 31;
    al[rr * 33 + dd] = abuf[(b * NODES + i0 + rr) * 32 + dd];
    cl[rr * 33 + dd] = cbuf[(b * NODES + j0 + rr) * 32 + dd];
  }
  __syncthreads();
  int ti = tid >> 4;
  int tj = tid & 15;
  float s1 = 0.f, s2 = 0.f, sg = 0.f;
#pragma unroll
  for (int d = 0; d < 32; d++) {
    float v = al[ti * 33 + d] + cl[tj * 33 + d];
    v = fmaxf(v, 0.f);
    s1 += v; s2 += v * v; sg += v * gwl[d];
  }
  float m = s1 * (1.f / 32.f);
  float var = s2 * (1.f / 32.f) - m * m;
  float rstd = rsqrtf(var + EPSV);
  float logit = rstd * (sg - m * gwl[32]) + gwl[33] + out2_b[0];
  float sig = 1.f / (1.f + __expf(-logit));
  out[(b * NODES + (i0 + ti)) * NODES + (j0 + tj)] = sig;
}

extern "C" void kernel_launch(void* const* d_in, const int* in_sizes, int n_in,
                              void* d_out, int out_size, void* d_ws, size_t ws_size,
                              hipStream_t stream) {
  const float* x          = (const float*)d_in[0];
  const int*   edge_index = (const int*)d_in[1];
  const float* edge_weight= (const float*)d_in[2];
  const float* in_proj_w  = (const float*)d_in[3];
  const float* in_proj_b  = (const float*)d_in[4];
  const float* tc_w       = (const float*)d_in[5];
  const float* tc_b       = (const float*)d_in[6];
  const float* cheb_w     = (const float*)d_in[7];
  const float* cheb_b     = (const float*)d_in[8];
  const float* bn_g       = (const float*)d_in[9];
  const float* bn_b       = (const float*)d_in[10];
  const float* ln_g       = (const float*)d_in[11];
  const float* ln_b       = (const float*)d_in[12];
  const float* out1_w     = (const float*)d_in[13];
  const float* out1_b     = (const float*)d_in[14];
  const float* oln_g      = (const float*)d_in[15];
  const float* oln_b      = (const float*)d_in[16];
  const float* out2_w     = (const float*)d_in[17];
  const float* out2_b     = (const float*)d_in[18];
  float* ws  = (float*)d_ws;
  float* out = (float*)d_out;

  hipLaunchKernelGGL(prep_kernel, dim3(668), dim3(256), 0, stream,
                     tc_w, cheb_w, in_proj_w, out1_w, oln_g, oln_b, out2_w, ws);
  hipLaunchKernelGGL(graph_kernel, dim3(1), dim3(1024), 0, stream, edge_index, edge_weight, ws);
  hipLaunchKernelGGL(inproj_kernel, dim3(2304), dim3(64), 0, stream, x, in_proj_b, ws);

  float* h   = ws + OFF_H;
  float* za  = ws + OFF_ZA;
  float* zb  = ws + OFF_ZB;
  float* agg = ws + OFF_AGG;
  const unsigned short* WB = (const unsigned short*)(ws + OFF_WT);

  for (int l = 0; l < 2; l++) {
    hipLaunchKernelGGL(tconv_kernel, dim3(1024), dim3(256), 0, stream,
                       h, za, WB + (l * 2 + 0) * 36864, tc_b + (l * 2 + 0) * 192);
    hipLaunchKernelGGL(agg_kernel, dim3(1536), dim3(256), 0, stream, za, agg, ws);
    hipLaunchKernelGGL(cheb_kernel, dim3(2304), dim3(64), 0, stream,
                       za, agg, zb, ws + OFF_THT + l * 8192, cheb_b + l * 64);
    hipLaunchKernelGGL(tconv_kernel, dim3(1024), dim3(256), 0, stream,
                       zb, za, WB + (l * 2 + 1) * 36864, tc_b + (l * 2 + 1) * 192);
    hipLaunchKernelGGL(bn_kernel, dim3(768), dim3(256), 0, stream,
                       za, h, bn_g + l * NODES, bn_b + l * NODES,
                       ln_g + l * 64, ln_b + l * 64);
  }

  hipLaunchKernelGGL(proj_kernel, dim3(768), dim3(256), 0, stream, out1_w, out1_b, ws);
  hipLaunchKernelGGL(pair_kernel, dim3(9216), dim3(256), 0, stream, ws, out2_b, out);
}

// Round 13
// 321.574 us; speedup vs baseline: 1.1750x; 1.1750x over previous
//
#include <hip/hip_runtime.h>
#include <math.h>

#define NODES 768
#define BB 4
#define TT 12
#define FF 32
#define HH 64
#define EE 24576
#define EPSV 1e-5f

typedef short bf16x8 __attribute__((ext_vector_type(8)));
typedef float f32x4  __attribute__((ext_vector_type(4)));

__device__ __forceinline__ unsigned short f2bf(float f) {
  union { float f; unsigned int u; } c; c.f = f;
  unsigned int u = c.u;
  unsigned int r = (u + 0x7FFFu + ((u >> 16) & 1u)) >> 16;   // RTNE
  return (unsigned short)r;
}

// ---- workspace layout (float index units) ----
constexpr int OFF_DEG    = 0;        // float[768]
constexpr int OFF_CNT    = 768;      // int[768]
constexpr int OFF_ROWPTR = 1600;     // int[769]
constexpr int OFF_OFF    = 2432;     // int[768]
constexpr int OFF_COLS   = 3200;     // int[24576]
constexpr int OFF_WSEW   = 27776;    // float[24576]
constexpr int OFF_WT     = 52352;    // ushort[4*36864] tconv B-fragments [lj][ks][nt][lane][j] (bf16)
constexpr int OFF_THT    = 199808;   // float[2*2*64*64] thetaT [l][k][o][i]
constexpr int OFF_WIN    = 216192;   // float[64*32]    in_proj^T [o][i]
constexpr int OFF_GW     = 222336;   // float[34]: gw[32], S1, S2
constexpr int OFF_H      = 222400;   // float[2359296]
constexpr int OFF_ZA     = 2581696;  // float[2359296]
constexpr int OFF_ZB     = 4940992;  // float[2359296]
constexpr int OFF_AGG    = 7300288;  // float[2359296]
constexpr int OFF_A      = 9661120;  // float[3072*32]
constexpr int OFF_C      = 9759424;  // float[3072*32]

// ---------------- prep: weight packing + zeroing + gw precompute ----------------
__global__ void prep_kernel(const float* __restrict__ tc_w, const float* __restrict__ cheb_w,
                            const float* __restrict__ in_proj_w, const float* __restrict__ out1_w,
                            const float* __restrict__ oln_g, const float* __restrict__ oln_b,
                            const float* __restrict__ out2_w, float* __restrict__ ws) {
  int idx = blockIdx.x * 256 + threadIdx.x;
  if (idx < 147456) {
    // bf16 B-fragment pack: [lj][ks(6)][nt(12)][lane(64)][j(8)]
    int lj = idx / 36864; int r = idx % 36864;
    int ks = r / 6144;    int r2 = r % 6144;
    int nt = r2 / 512;    int r3 = r2 % 512;
    int l  = r3 >> 3;     int j  = r3 & 7;
    int k  = ks * 32 + ((l >> 4) << 3) + j;   // K index 0..191
    int kk = k >> 6;      int in = k & 63;
    int col = nt * 16 + (l & 15);             // N index 0..191
    int g = col >> 6;     int o  = col & 63;
    float v = tc_w[(((lj * 3 + g) * 64 + o) * 64 + in) * 3 + kk];
    ((unsigned short*)(ws + OFF_WT))[idx] = f2bf(v);
  }
  int idx2 = idx - 147456;
  if (idx2 >= 0 && idx2 < 16384) {
    int i = idx2 & 63; int t = idx2 >> 6;
    int o = t & 63; t >>= 6;
    int k = t & 1; int l = t >> 1;
    ws[OFF_THT + idx2] = cheb_w[((l*2 + k)*64 + i)*64 + o];
  }
  int idx3 = idx2 - 16384;
  if (idx3 >= 0 && idx3 < 2048) {
    int i = idx3 & 31; int o = idx3 >> 5;
    ws[OFF_WIN + idx3] = in_proj_w[i*64 + o];
  }
  int idx5 = idx3 - 2048;
  if (idx5 >= 0 && idx5 < 768) {
    ws[OFF_DEG + idx5] = 0.0f;
    ((int*)ws)[OFF_CNT + idx5] = 0;
  }
  int idx6 = idx5 - 768;
  if (idx6 == 0) {
    float S1 = 0.f, S2 = 0.f;
    for (int d = 0; d < 32; d++) {
      float gw = oln_g[d] * out2_w[d];
      ws[OFF_GW + d] = gw;
      S1 += gw;
      S2 += oln_b[d] * out2_w[d];
    }
    ws[OFF_GW + 32] = S1;
    ws[OFF_GW + 33] = S2;
  }
}

// ---------------- degree + edge counts (96 blocks) ----------------
__global__ void count_kernel(const int* __restrict__ edge_index, const float* __restrict__ ew,
                             float* __restrict__ ws) {
  int e = blockIdx.x * 256 + threadIdx.x;
  if (e >= EE) return;
  int r = edge_index[e];
  atomicAdd(&ws[OFF_DEG + r], ew[e]);
  atomicAdd(&((int*)ws)[OFF_CNT + r], 1);
}

// ---------------- prefix scan over counts (1 block, 768 thr) ----------------
__global__ void scan_kernel(float* __restrict__ ws) {
  __shared__ int s[NODES];
  int t = threadIdx.x;
  int* counts = (int*)ws + OFF_CNT;
  int* rowptr = (int*)ws + OFF_ROWPTR;
  int* off    = (int*)ws + OFF_OFF;
  int c = counts[t];
  s[t] = c;
  __syncthreads();
  for (int d = 1; d < NODES; d <<= 1) {
    int v = (t >= d) ? s[t - d] : 0;
    __syncthreads();
    s[t] += v;
    __syncthreads();
  }
  rowptr[t + 1] = s[t];
  if (t == 0) rowptr[0] = 0;
  off[t] = s[t] - c;
}

// ---------------- scatter edges into CSR order (96 blocks; also computes lap_w) ----------------
__global__ void scatter_kernel(const int* __restrict__ edge_index, const float* __restrict__ ew,
                               float* __restrict__ ws) {
  int e = blockIdx.x * 256 + threadIdx.x;
  if (e >= EE) return;
  int r = edge_index[e];
  int c = edge_index[EE + e];
  float w = ew[e];
  float dr = ws[OFF_DEG + r], dc = ws[OFF_DEG + c];
  float dir = dr > 0.f ? rsqrtf(fmaxf(dr, 1e-12f)) : 0.f;
  float dic = dc > 0.f ? rsqrtf(fmaxf(dc, 1e-12f)) : 0.f;
  float lw = -dir * w * dic;
  int pos = atomicAdd(&((int*)ws)[OFF_OFF + r], 1);
  ((int*)ws)[OFF_COLS + pos] = c;
  ws[OFF_WSEW + pos] = lw;
}

// ---------------- in_proj: h = x @ W(32x64) + b  [o-split x4, reg-resident rows] ----------------
__global__ __launch_bounds__(64) void inproj_kernel(const float* __restrict__ x,
                                                    const float* __restrict__ in_proj_b,
                                                    float* __restrict__ ws) {
  int bid = blockIdx.x;
  int r0 = (bid >> 2) << 6;
  int o0 = (bid & 3) << 4;
  int row = r0 + threadIdx.x;
  float xr[32];
  const float4* xp = (const float4*)(x + row * 32);
#pragma unroll
  for (int i = 0; i < 8; i++) {
    float4 v = xp[i];
    xr[4*i] = v.x; xr[4*i+1] = v.y; xr[4*i+2] = v.z; xr[4*i+3] = v.w;
  }
  const float* WT = ws + OFF_WIN;
  float* h = ws + OFF_H;
  float4 res[4];
  float* rf = (float*)res;
#pragma unroll
  for (int oo = 0; oo < 16; oo++) {
    int o = o0 + oo;
    float acc = in_proj_b[o];
#pragma unroll
    for (int i = 0; i < 32; i++) acc += xr[i] * WT[o * 32 + i];
    rf[oo] = acc;
  }
  float4* op = (float4*)(h + row * 64 + o0);
#pragma unroll
  for (int q = 0; q < 4; q++) op[q] = res[q];
}

// ---------------- gated temporal conv via bf16 MFMA [3 pairs/block, grid 1024] ----------------
__global__ __launch_bounds__(256) void tconv_kernel(const float* __restrict__ src,
                                                    float* __restrict__ dst,
                                                    const unsigned short* __restrict__ WB,
                                                    const float* __restrict__ bias) {
  __shared__ unsigned short zls[3072];   // 6144 B: 3 pairs x 14 rows x 128 B (+tail slack)
  __shared__ float cbuf[12 * 192];       // 9216 B
  unsigned char* zb = (unsigned char*)zls;
  int tid = threadIdx.x;
  int lane = tid & 63;
  int w = tid >> 6;
  int P0 = blockIdx.x * 3;
  int b  = P0 / NODES;
  int n0 = P0 % NODES;

  // ---- preload B fragments: 6 ksteps x 3 owned ntiles ----
  bf16x8 bfr[6][3];
#pragma unroll
  for (int ks = 0; ks < 6; ks++) {
#pragma unroll
    for (int c = 0; c < 3; c++) {
      int nt = w * 3 + c;
      bfr[ks][c] = *(const bf16x8*)(WB + (((ks * 12 + nt) * 64 + lane) << 3));
    }
  }
  float B0 = bias[tid & 63];
  float B1 = bias[64 + (tid & 63)];
  float B2 = bias[128 + (tid & 63)];

  // ---- zero halo rows ts=0,13 per pair ----
  for (int e = tid; e < 384; e += 256) {
    int pl = e / 128; int rr = (e >> 6) & 1; int in = e & 63;
    int ts = rr ? 13 : 0;
    int off = pl * 1792 + ts * 128 + ((in * 2) ^ ((ts & 7) << 4));
    *(unsigned short*)(zb + off) = 0;
  }
  // ---- stage z vectorized: float4 load -> 2x u32 packed bf16 stores ----
  for (int e = tid; e < 576; e += 256) {
    int pl = e / 192; int rem = e % 192; int t = rem >> 4; int i4 = rem & 15;
    int c0 = i4 << 2;
    float4 v = *(const float4*)(src + ((b * TT + t) * NODES + n0 + pl) * HH + c0);
    int ts = t + 1;
    int base = pl * 1792 + ts * 128;
    unsigned int lo = ((unsigned int)f2bf(v.y) << 16) | f2bf(v.x);
    unsigned int hi = ((unsigned int)f2bf(v.w) << 16) | f2bf(v.z);
    *(unsigned int*)(zb + (base + (((c0    ) * 2) ^ ((ts & 7) << 4)))) = lo;
    *(unsigned int*)(zb + (base + (((c0 + 2) * 2) ^ ((ts & 7) << 4)))) = hi;
  }
  __syncthreads();

  int tb = (lane >> 4) << 2;
  int cc = lane & 15;
  for (int p = 0; p < 3; p++) {
    bf16x8 afr[6];
#pragma unroll
    for (int ks = 0; ks < 6; ks++) {
      int k0 = ks * 32 + ((lane >> 4) << 3);
      int kk = k0 >> 6; int in0 = k0 & 63;
      int ts = (lane & 15) + kk;
      int off = p * 1792 + ts * 128 + ((in0 * 2) ^ ((ts & 7) << 4));
      afr[ks] = *(const bf16x8*)(zb + off);
    }
    f32x4 a0 = {0.f, 0.f, 0.f, 0.f};
    f32x4 a1 = a0, a2 = a0;
#pragma unroll
    for (int ks = 0; ks < 6; ks++) {
      a0 = __builtin_amdgcn_mfma_f32_16x16x32_bf16(afr[ks], bfr[ks][0], a0, 0, 0, 0);
      a1 = __builtin_amdgcn_mfma_f32_16x16x32_bf16(afr[ks], bfr[ks][1], a1, 0, 0, 0);
      a2 = __builtin_amdgcn_mfma_f32_16x16x32_bf16(afr[ks], bfr[ks][2], a2, 0, 0, 0);
    }
    __syncthreads();   // previous pair's gating finished reading cbuf
#pragma unroll
    for (int r = 0; r < 4; r++) {
      int t = tb + r;
      if (t < 12) {
        cbuf[t * 192 + (w * 3 + 0) * 16 + cc] = a0[r];
        cbuf[t * 192 + (w * 3 + 1) * 16 + cc] = a1[r];
        cbuf[t * 192 + (w * 3 + 2) * 16 + cc] = a2[r];
      }
    }
    __syncthreads();
    int o = tid & 63;
    int n = n0 + p;
#pragma unroll
    for (int m = 0; m < 3; m++) {
      int t = (tid >> 6) + (m << 2);
      float v0 = cbuf[t * 192 + o]       + B0;
      float v1 = cbuf[t * 192 + 64 + o]  + B1;
      float v2 = cbuf[t * 192 + 128 + o] + B2;
      float g = 1.f / (1.f + __expf(-v1));
      dst[((b * TT + t) * NODES + n) * HH + o] = fmaxf(v0 * g + v2, 0.f);
    }
  }
}

// ---------------- graph aggregation [bt-split x2] ----------------
__global__ __launch_bounds__(256) void agg_kernel(const float* __restrict__ za,
                                                  float* __restrict__ agg,
                                                  const float* __restrict__ ws) {
  int n = blockIdx.x >> 1;
  int half = blockIdx.x & 1;
  const int* rowptr = (const int*)ws + OFF_ROWPTR;
  const int* cols = (const int*)ws + OFF_COLS;
  const float* wsrt = ws + OFF_WSEW;
  int e0 = rowptr[n], e1 = rowptr[n + 1];
  int tid = threadIdx.x;
  int hh = tid & 63;
  int bt0 = tid >> 6;
  float acc[6];
#pragma unroll
  for (int p = 0; p < 6; p++) acc[p] = 0.f;
  for (int e = e0; e < e1; e++) {
    int c = cols[e];
    float w = wsrt[e];
    const float* zp = za + c * HH + hh;
#pragma unroll
    for (int p = 0; p < 6; p++) {
      int bt = bt0 + (((half * 6) + p) << 2);
      acc[p] += w * zp[bt * NODES * HH];
    }
  }
#pragma unroll
  for (int p = 0; p < 6; p++) {
    int bt = bt0 + (((half * 6) + p) << 2);
    agg[(bt * NODES + n) * HH + hh] = acc[p];
  }
}

// ---------------- cheb combine [o-split x4, reg-resident rows] ----------------
__global__ __launch_bounds__(64) void cheb_kernel(const float* __restrict__ za,
                                                  const float* __restrict__ agg,
                                                  float* __restrict__ zb,
                                                  const float* __restrict__ thetaT,
                                                  const float* __restrict__ bias) {
  int bid = blockIdx.x;
  int r0 = (bid >> 2) << 6;
  int o0 = (bid & 3) << 4;
  int row = r0 + threadIdx.x;
  float xz[64], xa[64];
  const float4* zp = (const float4*)(za + row * 64);
  const float4* ap = (const float4*)(agg + row * 64);
#pragma unroll
  for (int i = 0; i < 16; i++) {
    float4 v = zp[i];
    xz[4*i] = v.x; xz[4*i+1] = v.y; xz[4*i+2] = v.z; xz[4*i+3] = v.w;
    float4 w = ap[i];
    xa[4*i] = w.x; xa[4*i+1] = w.y; xa[4*i+2] = w.z; xa[4*i+3] = w.w;
  }
  float4 res[4];
  float* rf = (float*)res;
#pragma unroll
  for (int oo = 0; oo < 16; oo++) {
    int o = o0 + oo;
    float acc = bias[o];
    const float* t0 = thetaT + o * 64;
    const float* t1 = thetaT + 4096 + o * 64;
#pragma unroll
    for (int i = 0; i < 64; i++) acc += xz[i] * t0[i] + xa[i] * t1[i];
    rf[oo] = fmaxf(acc, 0.f);
  }
  float4* op = (float4*)(zb + row * 64 + o0);
#pragma unroll
  for (int q = 0; q < 4; q++) op[q] = res[q];
}

// ---------------- fused BN stats + BN apply + LN + residual (per node) ----------------
__global__ __launch_bounds__(256) void bn_kernel(const float* __restrict__ z,
                                                 float* __restrict__ h,
                                                 const float* __restrict__ bn_g,
                                                 const float* __restrict__ bn_b,
                                                 const float* __restrict__ ln_g,
                                                 const float* __restrict__ ln_b) {
  __shared__ float zl[48 * 64];   // 12 KB node tile
  __shared__ float rs[4], rss[4];
  __shared__ float sstat[2];
  int n = blockIdx.x;
  int tid = threadIdx.x;
  int wave = tid >> 6, lane = tid & 63;
  float s = 0.f, ss = 0.f;
  for (int p = tid; p < 3072; p += 256) {
    int bt = p >> 6, hh = p & 63;
    float v = z[(bt * NODES + n) * HH + hh];
    zl[p] = v;
    s += v; ss += v * v;
  }
#pragma unroll
  for (int d = 32; d >= 1; d >>= 1) { s += __shfl_down(s, d, 64); ss += __shfl_down(ss, d, 64); }
  if (lane == 0) { rs[wave] = s; rss[wave] = ss; }
  __syncthreads();
  if (tid == 0) {
    float S = rs[0] + rs[1] + rs[2] + rs[3];
    float SS = rss[0] + rss[1] + rss[2] + rss[3];
    float m = S / 3072.f;
    float var = SS / 3072.f - m * m;
    sstat[0] = m; sstat[1] = rsqrtf(var + EPSV);
  }
  __syncthreads();
  float mu = sstat[0], rstd = sstat[1];
  float bg = bn_g[n] * rstd;
  float bbb = bn_b[n] - mu * bg;
  float lg = ln_g[lane], lb = ln_b[lane];
  for (int k = 0; k < 12; k++) {
    int bt = wave + (k << 2);
    float v = zl[bt * 64 + lane] * bg + bbb;
    float s1 = v, s2 = v * v;
#pragma unroll
    for (int d = 32; d >= 1; d >>= 1) { s1 += __shfl_xor(s1, d, 64); s2 += __shfl_xor(s2, d, 64); }
    float m = s1 * (1.f / 64.f);
    float var = s2 * (1.f / 64.f) - m * m;
    float r2 = rsqrtf(var + EPSV);
    v = (v - m) * r2 * lg + lb;
    h[(bt * NODES + n) * HH + lane] += v;
  }
}

// ---------------- out projection: one output per thread ----------------
__global__ __launch_bounds__(256) void proj_kernel(const float* __restrict__ out1_w,
                                                   const float* __restrict__ out1_b,
                                                   float* __restrict__ ws) {
  __shared__ float wl[128 * 32];   // raw [i][o] layout, 16 KB
  __shared__ float rl[4][64];
  int r0 = blockIdx.x * 4;
  int tid = threadIdx.x;
  const float* h = ws + OFF_H;
  for (int p = tid; p < 4096; p += 256) wl[p] = out1_w[p];
  {
    int rr = tid >> 6, ii = tid & 63;
    int row = r0 + rr;
    int b = row / NODES, n = row % NODES;
    rl[rr][ii] = h[((b * TT + (TT - 1)) * NODES + n) * 64 + ii];
  }
  __syncthreads();
  int rr = tid >> 6;        // wave = row
  int o = tid & 63;         // lane = output
  int part = o >> 5, oc = o & 31;
  float acc = part ? out1_b[oc] : 0.f;
  const float* wcol = wl + part * 64 * 32;
#pragma unroll
  for (int i = 0; i < 64; i++) acc += rl[rr][i] * wcol[i * 32 + oc];
  int row = r0 + rr;
  if (part == 0) (ws + OFF_A)[row * 32 + oc] = acc;
  else           (ws + OFF_C)[row * 32 + oc] = acc;
}

// ---------------- final pairwise head ----------------
__global__ __launch_bounds__(256) void pair_kernel(const float* __restrict__ ws,
                                                   const float* __restrict__ out2_b,
                                                   float* __restrict__ out) {
  __shared__ float al[16 * 33], cl[16 * 33], gwl[34];
  int bidx = blockIdx.x;
  int b = bidx / (48 * 48);
  int rem = bidx % (48 * 48);
  int i0 = (rem / 48) * 16;
  int j0 = (rem % 48) * 16;
  int tid = threadIdx.x;
  const float* abuf = ws + OFF_A;
  const float* cbuf = ws + OFF_C;
  if (tid < 34) gwl[tid] = ws[OFF_GW + tid];
  for (int p = tid; p < 512; p += 256) {
    int rr = p >> 5, dd = p & 31;
    al[rr * 33 + dd] = abuf[(b * NODES + i0 + rr) * 32 + dd];
    cl[rr * 33 + dd] = cbuf[(b * NODES + j0 + rr) * 32 + dd];
  }
  __syncthreads();
  int ti = tid >> 4;
  int tj = tid & 15;
  float s1 = 0.f, s2 = 0.f, sg = 0.f;
#pragma unroll
  for (int d = 0; d < 32; d++) {
    float v = al[ti * 33 + d] + cl[tj * 33 + d];
    v = fmaxf(v, 0.f);
    s1 += v; s2 += v * v; sg += v * gwl[d];
  }
  float m = s1 * (1.f / 32.f);
  float var = s2 * (1.f / 32.f) - m * m;
  float rstd = rsqrtf(var + EPSV);
  float logit = rstd * (sg - m * gwl[32]) + gwl[33] + out2_b[0];
  float sig = 1.f / (1.f + __expf(-logit));
  out[(b * NODES + (i0 + ti)) * NODES + (j0 + tj)] = sig;
}

extern "C" void kernel_launch(void* const* d_in, const int* in_sizes, int n_in,
                              void* d_out, int out_size, void* d_ws, size_t ws_size,
                              hipStream_t stream) {
  const float* x          = (const float*)d_in[0];
  const int*   edge_index = (const int*)d_in[1];
  const float* edge_weight= (const float*)d_in[2];
  const float* in_proj_w  = (const float*)d_in[3];
  const float* in_proj_b  = (const float*)d_in[4];
  const float* tc_w       = (const float*)d_in[5];
  const float* tc_b       = (const float*)d_in[6];
  const float* cheb_w     = (const float*)d_in[7];
  const float* cheb_b     = (const float*)d_in[8];
  const float* bn_g       = (const float*)d_in[9];
  const float* bn_b       = (const float*)d_in[10];
  const float* ln_g       = (const float*)d_in[11];
  const float* ln_b       = (const float*)d_in[12];
  const float* out1_w     = (const float*)d_in[13];
  const float* out1_b     = (const float*)d_in[14];
  const float* oln_g      = (const float*)d_in[15];
  const float* oln_b      = (const float*)d_in[16];
  const float* out2_w     = (const float*)d_in[17];
  const float* out2_b     = (const float*)d_in[18];
  float* ws  = (float*)d_ws;
  float* out = (float*)d_out;

  hipLaunchKernelGGL(prep_kernel, dim3(668), dim3(256), 0, stream,
                     tc_w, cheb_w, in_proj_w, out1_w, oln_g, oln_b, out2_w, ws);
  hipLaunchKernelGGL(count_kernel, dim3(96), dim3(256), 0, stream, edge_index, edge_weight, ws);
  hipLaunchKernelGGL(scan_kernel, dim3(1), dim3(768), 0, stream, ws);
  hipLaunchKernelGGL(scatter_kernel, dim3(96), dim3(256), 0, stream, edge_index, edge_weight, ws);
  hipLaunchKernelGGL(inproj_kernel, dim3(2304), dim3(64), 0, stream, x, in_proj_b, ws);

  float* h   = ws + OFF_H;
  float* za  = ws + OFF_ZA;
  float* zb  = ws + OFF_ZB;
  float* agg = ws + OFF_AGG;
  const unsigned short* WB = (const unsigned short*)(ws + OFF_WT);

  for (int l = 0; l < 2; l++) {
    hipLaunchKernelGGL(tconv_kernel, dim3(1024), dim3(256), 0, stream,
                       h, za, WB + (l * 2 + 0) * 36864, tc_b + (l * 2 + 0) * 192);
    hipLaunchKernelGGL(agg_kernel, dim3(1536), dim3(256), 0, stream, za, agg, ws);
    hipLaunchKernelGGL(cheb_kernel, dim3(2304), dim3(64), 0, stream,
                       za, agg, zb, ws + OFF_THT + l * 8192, cheb_b + l * 64);
    hipLaunchKernelGGL(tconv_kernel, dim3(1024), dim3(256), 0, stream,
                       zb, za, WB + (l * 2 + 1) * 36864, tc_b + (l * 2 + 1) * 192);
    hipLaunchKernelGGL(bn_kernel, dim3(768), dim3(256), 0, stream,
                       za, h, bn_g + l * NODES, bn_b + l * NODES,
                       ln_g + l * 64, ln_b + l * 64);
  }

  hipLaunchKernelGGL(proj_kernel, dim3(768), dim3(256), 0, stream, out1_w, out1_b, ws);
  hipLaunchKernelGGL(pair_kernel, dim3(9216), dim3(256), 0, stream, ws, out2_b, out);
}